// Round 8
// baseline (475.043 us; speedup 1.0000x reference)
//
#include <hip/hip_runtime.h>

// Problem constants (match reference setup_inputs)
constexpr int B = 64, T = 256, M = 16, A = 32, H = 64;
constexpr int NCOL  = M * H + H * H + H;  // 1024 + 4096 + 64 = 5184 used cols
constexpr int NCOLP = 5376;               // padded row stride: 21504 B = 21 x 1KB DMA
constexpr int NG = 81;                    // 16 J + 64 R + 1 o groups of 64 cols

// G layout (row-major): G[r * NCOLP + g*64 + c], r = b*chunk + tc.
// Row image: [J 1024 | R 4096 | o 64 | pad 192] -- exactly what scan DMAs.

// ---------------------------------------------------------------------------
// Gate kernel v9: lane = output column. W row in 32 VGPRs per lane (reused
// for 32 rows); x_a broadcast from 16KB LDS tile; softmax via 6-op shfl_xor
// sum (max-sub dropped: |logit| < 4, exp safe); store = 1 dword/lane =
// contiguous 256B run. No transpose, small LDS, high occupancy.
// ---------------------------------------------------------------------------
__global__ __launch_bounds__(256) void gate_kernel(
    const float* __restrict__ x_a,
    const float* __restrict__ Wj, const float* __restrict__ bj,
    const float* __restrict__ Wr, const float* __restrict__ br,
    const float* __restrict__ Wo, const float* __restrict__ bo,
    float* __restrict__ G, int t0, int chunk)
{
    const int g = blockIdx.x;
    const int tid = threadIdx.x;
    const int lane = tid & 63;
    const int wv = tid >> 6;

    __shared__ __align__(16) float xs[128][32];   // 16KB x-row tile

    const float* Wp; const float* bp; int row0;
    if (g < 16)      { Wp = Wj; bp = bj; row0 = g * H; }
    else if (g < 80) { Wp = Wr; bp = br; row0 = (g - 16) * H; }
    else             { Wp = Wo; bp = bo; row0 = 0; }

    // per-lane W row (128B) in registers, reused for all 32 rows
    float4 w[8];
    {
        const float4* wp = (const float4*)(Wp + (size_t)(row0 + lane) * A);
        #pragma unroll
        for (int j = 0; j < 8; ++j) w[j] = wp[j];
    }
    const float bl = bp[row0 + lane];

    // stage x tile: 128 rows x 32 floats; 2 threads per row, 4 float4 each
    {
        const int rl = tid >> 1, j0 = (tid & 1) * 4;
        const int r = blockIdx.y * 128 + rl;
        const int bb = r / chunk, tc = r % chunk;
        const float4* src = (const float4*)(x_a + ((size_t)bb * T + t0 + tc) * A);
        float4* dst = (float4*)&xs[rl][0];
        #pragma unroll
        for (int j = 0; j < 4; ++j) dst[j0 + j] = src[j0 + j];
    }
    __syncthreads();

    const int rbase = blockIdx.y * 128 + wv * 32;
    float* gout = G + (size_t)rbase * NCOLP + g * 64 + lane;

    if (g < 80) {   // softmax groups
        #pragma unroll 2
        for (int i = 0; i < 32; ++i) {
            const float4* xv = (const float4*)&xs[wv * 32 + i][0];  // uniform
            float s = bl;
            #pragma unroll
            for (int j = 0; j < 8; ++j) {
                float4 x = xv[j];
                s += x.x * w[j].x + x.y * w[j].y + x.z * w[j].z + x.w * w[j].w;
            }
            float e = __expf(s);        // |s| < ~4: no max-subtraction needed
            float sum = e;
            #pragma unroll
            for (int off = 1; off < 64; off <<= 1) sum += __shfl_xor(sum, off);
            gout[(size_t)i * NCOLP] = __fdividef(e, sum);   // 256B-coalesced
        }
    } else {        // out-gate sigmoid
        #pragma unroll 2
        for (int i = 0; i < 32; ++i) {
            const float4* xv = (const float4*)&xs[wv * 32 + i][0];
            float s = bl;
            #pragma unroll
            for (int j = 0; j < 8; ++j) {
                float4 x = xv[j];
                s += x.x * w[j].x + x.y * w[j].y + x.z * w[j].z + x.w * w[j].w;
            }
            gout[(size_t)i * NCOLP] = __fdividef(1.f, 1.f + __expf(-s));
        }
    }
}

// ---------------------------------------------------------------------------
// Scan kernel v7 (R5-proven, ~3us/dispatch): one wave per batch. G-row
// async-DMA'd to LDS (global_load_lds dwordx4, triple-buffered, counted
// vmcnt -- never 0 mid-loop). Lane l = (k-quad q=l&15, h-range hr=l>>4);
// b128 LDS reads; in-wave shfl_xor reduce. No barriers, no reg pressure.
// ---------------------------------------------------------------------------
__global__ __launch_bounds__(64, 1) void scan_kernel(
    const float* __restrict__ G,
    const float* __restrict__ x_m,
    const float* __restrict__ Wfc, const float* __restrict__ bfc,
    float* __restrict__ out, int t0, int chunk, int first)
{
    const int b = blockIdx.x;
    const int l = threadIdx.x;
    const int q = l & 15;    // k-quad: k = 4q..4q+3
    const int hr = l >> 4;   // h-range: h = hr*16 .. hr*16+15

    __shared__ __align__(16) float buf[3][NCOLP];   // 63KB triple buffer
    __shared__ __align__(16) float c_sh[64];
    __shared__ __align__(16) float xm_s[1024];      // chunk<=64

    float* cbase = out + B;  // c region: cbase[(b*T + t)*H + k]

    {   // stage x_m chunk (chunk*16 floats)
        const float4* src = (const float4*)(x_m + ((size_t)b * T + t0) * M);
        float4* dst = (float4*)xm_s;
        for (int i = l; i < chunk * 4; i += 64) dst[i] = src[i];
    }
    c_sh[l] = first ? 0.f : cbase[((size_t)b * T + (t0 - 1)) * H + l];
    const float4 wfc4 = *(const float4*)&Wfc[q * 4];
    const float bfc0 = bfc[0];
    asm volatile("s_waitcnt vmcnt(0) lgkmcnt(0)" ::: "memory");

#define DMA(tc_)                                                                \
    {                                                                           \
        const float* rp_ = G + (size_t)(b * chunk + (tc_)) * NCOLP;             \
        float* lb_ = &buf[(tc_) % 3][0];                                        \
        _Pragma("unroll")                                                       \
        for (int i_ = 0; i_ < 21; ++i_)                                         \
            __builtin_amdgcn_global_load_lds(                                   \
                (const __attribute__((address_space(1))) unsigned int*)         \
                    (rp_ + i_ * 256 + l * 4),                                   \
                (__attribute__((address_space(3))) unsigned int*)               \
                    (lb_ + i_ * 256), 16, 0, 0);                                \
    }

    DMA(0); DMA(1); DMA(2);

    for (int tc = 0; tc < chunk; ++tc) {
        // counted waits: conservative (store insts add slack, never deficit)
        if (tc + 3 <= chunk)      asm volatile("s_waitcnt vmcnt(42)" ::: "memory");
        else if (tc + 2 == chunk) asm volatile("s_waitcnt vmcnt(21)" ::: "memory");
        else                      asm volatile("s_waitcnt vmcnt(0)"  ::: "memory");
        __builtin_amdgcn_sched_barrier(0);

        const float* bp2 = &buf[tc % 3][0];

        float cc[16];
        #pragma unroll
        for (int i = 0; i < 16; ++i) cc[i] = c_sh[hr * 16 + i];
        float xm[4];
        #pragma unroll
        for (int j = 0; j < 4; ++j) xm[j] = xm_s[tc * 16 + hr * 4 + j];

        float a0 = 0.f, a1 = 0.f, a2 = 0.f, a3 = 0.f;
        #pragma unroll
        for (int j = 0; j < 4; ++j) {
            const float4 jv = *(const float4*)&bp2[(hr * 4 + j) * 64 + q * 4];
            a0 += xm[j] * jv.x; a1 += xm[j] * jv.y;
            a2 += xm[j] * jv.z; a3 += xm[j] * jv.w;
        }
        #pragma unroll
        for (int i = 0; i < 16; ++i) {
            const float4 rv = *(const float4*)&bp2[1024 + (hr * 16 + i) * 64 + q * 4];
            a0 += cc[i] * rv.x; a1 += cc[i] * rv.y;
            a2 += cc[i] * rv.z; a3 += cc[i] * rv.w;
        }
        const float4 o4 = *(const float4*)&bp2[5120 + q * 4];

        // reduce partials across the 4 h-ranges (lanes ^16, ^32)
        a0 += __shfl_xor(a0, 16); a1 += __shfl_xor(a1, 16);
        a2 += __shfl_xor(a2, 16); a3 += __shfl_xor(a3, 16);
        a0 += __shfl_xor(a0, 32); a1 += __shfl_xor(a1, 32);
        a2 += __shfl_xor(a2, 32); a3 += __shfl_xor(a3, 32);

        const float cn0 = (1.f - o4.x) * a0;
        const float cn1 = (1.f - o4.y) * a1;
        const float cn2 = (1.f - o4.z) * a2;
        const float cn3 = (1.f - o4.w) * a3;

        if (hr == 0) {   // 16 lanes: write c_sh + coalesced 256B global store
            *(float4*)&c_sh[q * 4] = make_float4(cn0, cn1, cn2, cn3);
            *(float4*)(cbase + ((size_t)b * T + t0 + tc) * H + q * 4) =
                make_float4(cn0, cn1, cn2, cn3);
        }
        if (t0 + tc == T - 1) {  // fused fc on last timestep
            float v = o4.x * a0 * wfc4.x + o4.y * a1 * wfc4.y +
                      o4.z * a2 * wfc4.z + o4.w * a3 * wfc4.w;
            v += __shfl_xor(v, 1); v += __shfl_xor(v, 2);
            v += __shfl_xor(v, 4); v += __shfl_xor(v, 8);
            if (l == 0) out[b] = v + bfc0;
        }

        if (tc + 3 < chunk) {
            asm volatile("s_waitcnt lgkmcnt(0)" ::: "memory");  // LDS reads done
            DMA(tc + 3);
        }
    }
#undef DMA
}

// ---------------------------------------------------------------------------
extern "C" void kernel_launch(void* const* d_in, const int* in_sizes, int n_in,
                              void* d_out, int out_size, void* d_ws, size_t ws_size,
                              hipStream_t stream) {
    const float* x_m = (const float*)d_in[0];
    const float* x_a = (const float*)d_in[1];
    const float* Wj  = (const float*)d_in[2];
    const float* bj  = (const float*)d_in[3];
    const float* Wr  = (const float*)d_in[4];
    const float* br  = (const float*)d_in[5];
    const float* Wo  = (const float*)d_in[6];
    const float* bo  = (const float*)d_in[7];
    const float* Wfc = (const float*)d_in[8];
    const float* bfc = (const float*)d_in[9];
    float* out = (float*)d_out;
    float* G   = (float*)d_ws;

    // time-chunk: prefer 64 (88MB G), shrink to fit ws; keep >= 8
    int chunk = 64;
    while (chunk > 8 && (size_t)B * chunk * NCOLP * sizeof(float) > ws_size) chunk >>= 1;

    for (int t0 = 0; t0 < T; t0 += chunk) {
        gate_kernel<<<dim3(NG, (B * chunk) / 128), 256, 0, stream>>>(
            x_a, Wj, bj, Wr, br, Wo, bo, G, t0, chunk);
        scan_kernel<<<64, 64, 0, stream>>>(
            G, x_m, Wfc, bfc, out, t0, chunk, t0 == 0 ? 1 : 0);
    }
}

// Round 9
// 398.604 us; speedup vs baseline: 1.1918x; 1.1918x over previous
//
#include <hip/hip_runtime.h>

// Problem constants (match reference setup_inputs)
constexpr int B = 64, T = 256, M = 16, A = 32, H = 64;
constexpr int NCOL  = M * H + H * H + H;  // 1024 + 4096 + 64 = 5184 used cols
constexpr int NCOLP = 5376;               // padded row stride: 21504 B = 21 x 1KB DMA
constexpr int NG = 81;                    // 16 J + 64 R + 1 o groups of 64 cols

// G layout (row-major): G[r * NCOLP + g*64 + c], r = b*chunk + tc.
// Row image: [J 1024 | R 4096 | o 64 | pad 192] -- exactly what scan DMAs.

// ---------------------------------------------------------------------------
// Gate kernel v11 (R4-proven structure, tuned): thread = row. acc[64] in
// regs, softmax THREAD-LOCAL (no cross-lane ops), W broadcast from LDS.
// Store via per-wave [64][20] tile: 20 floats = 80B row stride -> every
// float4 16B-aligned (true b128 ops); read phase spreads 8 lanes/bank-quad.
// LDS 28.5KB -> 5 blocks/CU resident, ~20 waves/CU.
// ---------------------------------------------------------------------------
__device__ __forceinline__ void softmax64(float (&acc)[64]) {
    float t32[32];
    #pragma unroll
    for (int i = 0; i < 32; ++i) t32[i] = fmaxf(acc[i], acc[i + 32]);
    #pragma unroll
    for (int i = 0; i < 16; ++i) t32[i] = fmaxf(t32[i], t32[i + 16]);
    #pragma unroll
    for (int i = 0; i < 8; ++i)  t32[i] = fmaxf(t32[i], t32[i + 8]);
    #pragma unroll
    for (int i = 0; i < 4; ++i)  t32[i] = fmaxf(t32[i], t32[i + 4]);
    float mx = fmaxf(fmaxf(t32[0], t32[1]), fmaxf(t32[2], t32[3]));
    float s0 = 0.f, s1 = 0.f, s2 = 0.f, s3 = 0.f;
    #pragma unroll
    for (int i = 0; i < 16; ++i) {
        acc[4*i+0] = __expf(acc[4*i+0] - mx); s0 += acc[4*i+0];
        acc[4*i+1] = __expf(acc[4*i+1] - mx); s1 += acc[4*i+1];
        acc[4*i+2] = __expf(acc[4*i+2] - mx); s2 += acc[4*i+2];
        acc[4*i+3] = __expf(acc[4*i+3] - mx); s3 += acc[4*i+3];
    }
    float inv = 1.f / ((s0 + s1) + (s2 + s3));
    #pragma unroll
    for (int c = 0; c < 64; ++c) acc[c] *= inv;
}

__global__ __launch_bounds__(256, 2) void gate_kernel(
    const float* __restrict__ x_a,
    const float* __restrict__ Wj, const float* __restrict__ bj,
    const float* __restrict__ Wr, const float* __restrict__ br,
    const float* __restrict__ Wo, const float* __restrict__ bo,
    float* __restrict__ G, int t0, int chunk)
{
    const int g = blockIdx.x;
    const int tid = threadIdx.x;
    const int lane = tid & 63;
    const int wv = tid >> 6;

    __shared__ float4 W4[512];          // 8KB: W[c] row-quad j at W4[c*8+j]
    __shared__ float bs[64];
    __shared__ float tr[4][64][20];     // 20.5KB: 80B rows, b128-aligned

    const float* Wp; const float* bp; int row0;
    if (g < 16)      { Wp = Wj; bp = bj; row0 = g * H; }
    else if (g < 80) { Wp = Wr; bp = br; row0 = (g - 16) * H; }
    else             { Wp = Wo; bp = bo; row0 = 0; }

    {   // cooperative W stage: 512 float4 by 256 threads (2 each) + bias
        const float4* src = (const float4*)(Wp + (size_t)row0 * A);
        W4[tid * 2]     = src[tid * 2];
        W4[tid * 2 + 1] = src[tid * 2 + 1];
        if (tid < 64) bs[tid] = bp[row0 + tid];
    }

    // this thread's row: contiguous 128B load (wave = 8KB contiguous)
    const int r0 = blockIdx.y * 256 + tid;
    const int bb = r0 / chunk, tcc = r0 % chunk;
    float4 xa[8];
    {
        const float4* src = (const float4*)(x_a + ((size_t)bb * T + t0 + tcc) * A);
        #pragma unroll
        for (int j = 0; j < 8; ++j) xa[j] = src[j];
    }
    __syncthreads();

    float acc[64];
    #pragma unroll
    for (int c = 0; c < 64; ++c) {
        float s = bs[c];
        #pragma unroll
        for (int j = 0; j < 8; ++j) {
            float4 w = W4[c * 8 + j];   // wave-uniform -> LDS broadcast
            s += xa[j].x * w.x + xa[j].y * w.y + xa[j].z * w.z + xa[j].w * w.w;
        }
        acc[c] = s;
    }

    if (g < 80) { softmax64(acc); }
    else {
        #pragma unroll
        for (int c = 0; c < 64; ++c) acc[c] = 1.f / (1.f + __expf(-acc[c]));
    }

    // store via per-wave LDS tile, 16 cols per pass, 64B-run global stores
    const int sr = lane >> 2, sc = lane & 3;
    const int rowg = blockIdx.y * 256 + wv * 64;
    float* gp = G + (size_t)(rowg + sr) * NCOLP + g * 64 + sc * 4;
    #pragma unroll
    for (int cc = 0; cc < 4; ++cc) {
        #pragma unroll
        for (int q = 0; q < 4; ++q)
            *(float4*)&tr[wv][lane][q * 4] = make_float4(
                acc[cc*16 + q*4 + 0], acc[cc*16 + q*4 + 1],
                acc[cc*16 + q*4 + 2], acc[cc*16 + q*4 + 3]);
        // same-wave DS write->read ordering (cross-lane dep invisible to
        // compiler); wave-lockstep + in-order DS pipe covers the HW side
        asm volatile("s_waitcnt lgkmcnt(0)" ::: "memory");
        __builtin_amdgcn_sched_barrier(0);
        #pragma unroll
        for (int i = 0; i < 4; ++i) {
            float4 v = *(const float4*)&tr[wv][i * 16 + sr][sc * 4];
            *(float4*)(gp + (size_t)(i * 16) * NCOLP + cc * 16) = v;
        }
        asm volatile("s_waitcnt lgkmcnt(0)" ::: "memory");  // reads done before reuse
        __builtin_amdgcn_sched_barrier(0);
    }
}

// ---------------------------------------------------------------------------
// Scan kernel v7 (R5-proven): one wave per batch. G-row async-DMA'd to LDS
// (global_load_lds dwordx4, triple-buffered, counted vmcnt -- never 0
// mid-loop). Lane l = (k-quad q=l&15, h-range hr=l>>4); b128 LDS reads;
// in-wave shfl_xor reduce. No barriers, no register pressure.
// ---------------------------------------------------------------------------
__global__ __launch_bounds__(64, 1) void scan_kernel(
    const float* __restrict__ G,
    const float* __restrict__ x_m,
    const float* __restrict__ Wfc, const float* __restrict__ bfc,
    float* __restrict__ out, int t0, int chunk, int first)
{
    const int b = blockIdx.x;
    const int l = threadIdx.x;
    const int q = l & 15;    // k-quad: k = 4q..4q+3
    const int hr = l >> 4;   // h-range: h = hr*16 .. hr*16+15

    __shared__ __align__(16) float buf[3][NCOLP];   // 63KB triple buffer
    __shared__ __align__(16) float c_sh[64];
    __shared__ __align__(16) float xm_s[1024];      // chunk<=64

    float* cbase = out + B;  // c region: cbase[(b*T + t)*H + k]

    {   // stage x_m chunk (chunk*16 floats)
        const float4* src = (const float4*)(x_m + ((size_t)b * T + t0) * M);
        float4* dst = (float4*)xm_s;
        for (int i = l; i < chunk * 4; i += 64) dst[i] = src[i];
    }
    c_sh[l] = first ? 0.f : cbase[((size_t)b * T + (t0 - 1)) * H + l];
    const float4 wfc4 = *(const float4*)&Wfc[q * 4];
    const float bfc0 = bfc[0];
    asm volatile("s_waitcnt vmcnt(0) lgkmcnt(0)" ::: "memory");

#define DMA(tc_)                                                                \
    {                                                                           \
        const float* rp_ = G + (size_t)(b * chunk + (tc_)) * NCOLP;             \
        float* lb_ = &buf[(tc_) % 3][0];                                        \
        _Pragma("unroll")                                                       \
        for (int i_ = 0; i_ < 21; ++i_)                                         \
            __builtin_amdgcn_global_load_lds(                                   \
                (const __attribute__((address_space(1))) unsigned int*)         \
                    (rp_ + i_ * 256 + l * 4),                                   \
                (__attribute__((address_space(3))) unsigned int*)               \
                    (lb_ + i_ * 256), 16, 0, 0);                                \
    }

    DMA(0); DMA(1); DMA(2);

    for (int tc = 0; tc < chunk; ++tc) {
        // counted waits: conservative (store insts add slack, never deficit)
        if (tc + 3 <= chunk)      asm volatile("s_waitcnt vmcnt(42)" ::: "memory");
        else if (tc + 2 == chunk) asm volatile("s_waitcnt vmcnt(21)" ::: "memory");
        else                      asm volatile("s_waitcnt vmcnt(0)"  ::: "memory");
        __builtin_amdgcn_sched_barrier(0);

        const float* bp2 = &buf[tc % 3][0];

        float cc[16];
        #pragma unroll
        for (int i = 0; i < 16; ++i) cc[i] = c_sh[hr * 16 + i];
        float xm[4];
        #pragma unroll
        for (int j = 0; j < 4; ++j) xm[j] = xm_s[tc * 16 + hr * 4 + j];

        float a0 = 0.f, a1 = 0.f, a2 = 0.f, a3 = 0.f;
        #pragma unroll
        for (int j = 0; j < 4; ++j) {
            const float4 jv = *(const float4*)&bp2[(hr * 4 + j) * 64 + q * 4];
            a0 += xm[j] * jv.x; a1 += xm[j] * jv.y;
            a2 += xm[j] * jv.z; a3 += xm[j] * jv.w;
        }
        #pragma unroll
        for (int i = 0; i < 16; ++i) {
            const float4 rv = *(const float4*)&bp2[1024 + (hr * 16 + i) * 64 + q * 4];
            a0 += cc[i] * rv.x; a1 += cc[i] * rv.y;
            a2 += cc[i] * rv.z; a3 += cc[i] * rv.w;
        }
        const float4 o4 = *(const float4*)&bp2[5120 + q * 4];

        // reduce partials across the 4 h-ranges (lanes ^16, ^32)
        a0 += __shfl_xor(a0, 16); a1 += __shfl_xor(a1, 16);
        a2 += __shfl_xor(a2, 16); a3 += __shfl_xor(a3, 16);
        a0 += __shfl_xor(a0, 32); a1 += __shfl_xor(a1, 32);
        a2 += __shfl_xor(a2, 32); a3 += __shfl_xor(a3, 32);

        const float cn0 = (1.f - o4.x) * a0;
        const float cn1 = (1.f - o4.y) * a1;
        const float cn2 = (1.f - o4.z) * a2;
        const float cn3 = (1.f - o4.w) * a3;

        if (hr == 0) {   // 16 lanes: write c_sh + coalesced 256B global store
            *(float4*)&c_sh[q * 4] = make_float4(cn0, cn1, cn2, cn3);
            *(float4*)(cbase + ((size_t)b * T + t0 + tc) * H + q * 4) =
                make_float4(cn0, cn1, cn2, cn3);
        }
        if (t0 + tc == T - 1) {  // fused fc on last timestep
            float v = o4.x * a0 * wfc4.x + o4.y * a1 * wfc4.y +
                      o4.z * a2 * wfc4.z + o4.w * a3 * wfc4.w;
            v += __shfl_xor(v, 1); v += __shfl_xor(v, 2);
            v += __shfl_xor(v, 4); v += __shfl_xor(v, 8);
            if (l == 0) out[b] = v + bfc0;
        }

        if (tc + 3 < chunk) {
            asm volatile("s_waitcnt lgkmcnt(0)" ::: "memory");  // LDS reads done
            DMA(tc + 3);
        }
    }
#undef DMA
}

// ---------------------------------------------------------------------------
extern "C" void kernel_launch(void* const* d_in, const int* in_sizes, int n_in,
                              void* d_out, int out_size, void* d_ws, size_t ws_size,
                              hipStream_t stream) {
    const float* x_m = (const float*)d_in[0];
    const float* x_a = (const float*)d_in[1];
    const float* Wj  = (const float*)d_in[2];
    const float* bj  = (const float*)d_in[3];
    const float* Wr  = (const float*)d_in[4];
    const float* br  = (const float*)d_in[5];
    const float* Wo  = (const float*)d_in[6];
    const float* bo  = (const float*)d_in[7];
    const float* Wfc = (const float*)d_in[8];
    const float* bfc = (const float*)d_in[9];
    float* out = (float*)d_out;
    float* G   = (float*)d_ws;

    // time-chunk: prefer 64 (88MB G), shrink to fit ws; keep >= 8
    int chunk = 64;
    while (chunk > 8 && (size_t)B * chunk * NCOLP * sizeof(float) > ws_size) chunk >>= 1;

    for (int t0 = 0; t0 < T; t0 += chunk) {
        gate_kernel<<<dim3(NG, (B * chunk) / 256), 256, 0, stream>>>(
            x_a, Wj, bj, Wr, br, Wo, bo, G, t0, chunk);
        scan_kernel<<<64, 64, 0, stream>>>(
            G, x_m, Wfc, bfc, out, t0, chunk, t0 == 0 ? 1 : 0);
    }
}

// Round 10
// 272.935 us; speedup vs baseline: 1.7405x; 1.4604x over previous
//
#include <hip/hip_runtime.h>

// Problem constants (match reference setup_inputs)
constexpr int B = 64, T = 256, M = 16, A = 32, H = 64;
constexpr int NGRP = 81;                    // 16 J + 64 R + 1 o groups of 64 gate-cols
constexpr int ROWBYTES = NGRP * 2048;       // 165,888 B per 16-row tile (81 x 16t x 64gc x bf16)
constexpr int STEPB = 11264;                // LDS bytes per scan step (11 x 1KB DMA)

typedef __attribute__((ext_vector_type(8))) short bf16x8;
typedef __attribute__((ext_vector_type(4))) float f32x4;

// ws layout (all 1024-aligned)
constexpr size_t OW = 0;                               // Wb  bf16 [5184][32]
constexpr size_t OX = 332800;                          // xb  bf16 [B*T][32]
constexpr size_t OB = OX + (size_t)B * T * A * 2;      // bcat f32 [5184]   (=1,381,376)
constexpr size_t OG = OB + 21504;                      // G tiles           (=1,402,880)

// G tiling: G[rtile][g][ct][t16][gc16] bf16; rtile = global_row/16 where
// global_row r = b*chunk + tc. Scan gathers one t-slice per step via
// per-lane global_load_lds sources; resulting LDS image is row-major
// bf16[5184] = [J 16x64 | R 64x64 | o 64].

__device__ __forceinline__ float blo(unsigned u) { return __builtin_bit_cast(float, u << 16); }
__device__ __forceinline__ float bhi(unsigned u) { return __builtin_bit_cast(float, u & 0xffff0000u); }

// ---------------------------------------------------------------------------
// Prep: convert W (Wj|Wr|Wo) and x_a to bf16; concat biases to f32 array.
// ---------------------------------------------------------------------------
__global__ __launch_bounds__(256) void prep_kernel(
    const float* __restrict__ x_a,
    const float* __restrict__ Wj, const float* __restrict__ Wr,
    const float* __restrict__ Wo,
    const float* __restrict__ bj, const float* __restrict__ br,
    const float* __restrict__ bo, unsigned char* ws)
{
    const int nW = 5184 * 32, nX = B * T * A, nB = 5184;
    int idx = blockIdx.x * 256 + threadIdx.x;
    if (idx >= nW + nX + nB) return;
    if (idx < nW + nX) {
        float v;
        ushort* dst;
        if (idx < nW) {
            int row = idx >> 5;
            v = (row < 1024) ? Wj[idx] : (row < 5120) ? Wr[idx - 1024 * 32] : Wo[idx - 5120 * 32];
            dst = (ushort*)(ws + OW) + idx;
        } else {
            v = x_a[idx - nW];
            dst = (ushort*)(ws + OX) + (idx - nW);
        }
        unsigned u = __builtin_bit_cast(unsigned, v);
        *dst = (ushort)((u + 0x7fffu + ((u >> 16) & 1u)) >> 16);   // RNE
    } else {
        int row = idx - nW - nX;
        float v = (row < 1024) ? bj[row] : (row < 5120) ? br[row - 1024] : bo[row - 5120];
        ((float*)(ws + OB))[row] = v;
    }
}

// ---------------------------------------------------------------------------
// Gate kernel (MFMA): block = 32 rows (2 x 16-row tiles) x all 81 groups.
// Swapped GEMM: D[gc][t] = mfma(A = W-slab 16x32, B = x-tile 32x16).
// D lane layout: t = lane&15, gc = 4*(lane>>4)+reg  ->  softmax over gc is
// lane-local 16 values + shfl_xor(16,32). Store = uint2/lane, 512B
// contiguous per inst, in D-native G tiling (no transpose, no LDS).
// ---------------------------------------------------------------------------
__global__ __launch_bounds__(256) void gate_kernel(
    unsigned char* ws, int t0, int chunk)
{
    const int tid = threadIdx.x, lane = tid & 63, wv = tid >> 6;
    const int l15 = lane & 15, l4 = lane >> 4;
    const ushort* Wb = (const ushort*)(ws + OW);
    const ushort* xb = (const ushort*)(ws + OX);
    const float*  bc = (const float*)(ws + OB);
    unsigned char* G = ws + OG;

    const int r0 = blockIdx.x * 32;                 // 32 consecutive rows, same batch
    const int bb = r0 / chunk, tcc = r0 % chunk;
    const long xrow0 = (long)bb * T + t0 + tcc;

    const bf16x8 bx0 = *(const bf16x8*)(xb + (xrow0 + l15) * 32 + l4 * 8);
    const bf16x8 bx1 = *(const bf16x8*)(xb + (xrow0 + 16 + l15) * 32 + l4 * 8);

    const int gbeg = (wv == 0) ? 0 : 21 + (wv - 1) * 20;
    const int gend = (wv == 0) ? 21 : gbeg + 20;

    const size_t rtb0 = (size_t)(r0 >> 4) * ROWBYTES;
    const f32x4 zero = {0.f, 0.f, 0.f, 0.f};

    for (int g = gbeg; g < gend; ++g) {
        f32x4 d0[4], d1[4];
        #pragma unroll
        for (int ct = 0; ct < 4; ++ct) {
            const bf16x8 aW =
                *(const bf16x8*)(Wb + (size_t)(g * 64 + ct * 16 + l15) * 32 + l4 * 8);
            d0[ct] = __builtin_amdgcn_mfma_f32_16x16x32_bf16(aW, bx0, zero, 0, 0, 0);
            d1[ct] = __builtin_amdgcn_mfma_f32_16x16x32_bf16(aW, bx1, zero, 0, 0, 0);
            const float4 bv = *(const float4*)(bc + g * 64 + ct * 16 + l4 * 4);
            d0[ct][0] += bv.x; d0[ct][1] += bv.y; d0[ct][2] += bv.z; d0[ct][3] += bv.w;
            d1[ct][0] += bv.x; d1[ct][1] += bv.y; d1[ct][2] += bv.z; d1[ct][3] += bv.w;
        }

        if (g < 80) {   // softmax over the 64 gate-cols (fixed t per lane)
            float s0 = 0.f, s1 = 0.f;
            #pragma unroll
            for (int ct = 0; ct < 4; ++ct)
                #pragma unroll
                for (int j = 0; j < 4; ++j) {
                    d0[ct][j] = __expf(d0[ct][j]); s0 += d0[ct][j];
                    d1[ct][j] = __expf(d1[ct][j]); s1 += d1[ct][j];
                }
            s0 += __shfl_xor(s0, 16); s0 += __shfl_xor(s0, 32);
            s1 += __shfl_xor(s1, 16); s1 += __shfl_xor(s1, 32);
            const float i0 = __fdividef(1.f, s0), i1 = __fdividef(1.f, s1);
            #pragma unroll
            for (int ct = 0; ct < 4; ++ct)
                #pragma unroll
                for (int j = 0; j < 4; ++j) { d0[ct][j] *= i0; d1[ct][j] *= i1; }
        } else {        // out-gate sigmoid
            #pragma unroll
            for (int ct = 0; ct < 4; ++ct)
                #pragma unroll
                for (int j = 0; j < 4; ++j) {
                    d0[ct][j] = __fdividef(1.f, 1.f + __expf(-d0[ct][j]));
                    d1[ct][j] = __fdividef(1.f, 1.f + __expf(-d1[ct][j]));
                }
        }

        // pack to bf16 pairs and store (D-native tiling, 512B/inst contiguous)
        unsigned char* gb0 = G + rtb0 + (size_t)g * 2048 + l15 * 32 + l4 * 8;
        #pragma unroll
        for (int ct = 0; ct < 4; ++ct) {
            unsigned lo0, hi0, lo1, hi1;
            asm volatile("v_cvt_pk_bf16_f32 %0, %1, %2" : "=v"(lo0) : "v"(d0[ct][0]), "v"(d0[ct][1]));
            asm volatile("v_cvt_pk_bf16_f32 %0, %1, %2" : "=v"(hi0) : "v"(d0[ct][2]), "v"(d0[ct][3]));
            asm volatile("v_cvt_pk_bf16_f32 %0, %1, %2" : "=v"(lo1) : "v"(d1[ct][0]), "v"(d1[ct][1]));
            asm volatile("v_cvt_pk_bf16_f32 %0, %1, %2" : "=v"(hi1) : "v"(d1[ct][2]), "v"(d1[ct][3]));
            *(uint2*)(gb0 + ct * 512)            = make_uint2(lo0, hi0);
            *(uint2*)(gb0 + ROWBYTES + ct * 512) = make_uint2(lo1, hi1);
        }
    }
}

// ---------------------------------------------------------------------------
// Scan kernel: one wave per batch (R5-proven skeleton). Per step, 11
// global_load_lds gather the t-slice from the tiled-bf16 G into a row-major
// LDS image (triple-buffered, counted vmcnt 22/11/0). bf16 b64 reads +
// shift-extract; shfl_xor reduce; fp32 math throughout.
// ---------------------------------------------------------------------------
__global__ __launch_bounds__(64, 1) void scan_kernel(
    const unsigned char* __restrict__ ws,
    const float* __restrict__ x_m,
    const float* __restrict__ Wfc, const float* __restrict__ bfc,
    float* __restrict__ out, int t0, int chunk, int first)
{
    const int b = blockIdx.x, l = threadIdx.x;
    const int q = l & 15, hr = l >> 4;
    const unsigned char* G = ws + OG;

    __shared__ __align__(16) unsigned char buf[3][STEPB];   // 33.8KB
    __shared__ __align__(16) float c_sh[64];
    __shared__ __align__(16) float xm_s[4096];              // chunk<=256

    float* cbase = out + B;   // c region: cbase[(b*T + t)*H + k]

    {   // stage x_m chunk
        const float4* src = (const float4*)(x_m + ((size_t)b * T + t0) * M);
        float4* dst = (float4*)xm_s;
        for (int i = l; i < chunk * 4; i += 64) dst[i] = src[i];
    }
    c_sh[l] = first ? 0.f : cbase[((size_t)b * T + (t0 - 1)) * H + l];
    const float4 wfc4 = *(const float4*)&Wfc[q * 4];
    const float bfc0 = bfc[0];

    // per-lane gather offsets: granule (16B) -> (g, ct, half) in the tile
    int goff[11];
    #pragma unroll
    for (int i = 0; i < 11; ++i) {
        int gran = i * 64 + l; if (gran > 647) gran = 647;
        const int gg = gran >> 3, c8 = gran & 7;
        goff[i] = gg * 2048 + (c8 >> 1) * 512 + (c8 & 1) * 16;
    }
    asm volatile("s_waitcnt vmcnt(0) lgkmcnt(0)" ::: "memory");

#define DMA(tc_)                                                                \
    {                                                                           \
        const int srow_ = b * chunk + (tc_);                                    \
        const unsigned char* rb_ =                                              \
            G + (size_t)(srow_ >> 4) * ROWBYTES + (srow_ & 15) * 32;            \
        unsigned char* lb_ = &buf[(tc_) % 3][0];                                \
        _Pragma("unroll")                                                       \
        for (int i_ = 0; i_ < 11; ++i_)                                         \
            __builtin_amdgcn_global_load_lds(                                   \
                (const __attribute__((address_space(1))) unsigned int*)         \
                    (rb_ + goff[i_]),                                           \
                (__attribute__((address_space(3))) unsigned int*)               \
                    (lb_ + i_ * 1024), 16, 0, 0);                               \
    }

    DMA(0); DMA(1); DMA(2);

    for (int tc = 0; tc < chunk; ++tc) {
        if (tc + 3 <= chunk)      asm volatile("s_waitcnt vmcnt(22)" ::: "memory");
        else if (tc + 2 == chunk) asm volatile("s_waitcnt vmcnt(11)" ::: "memory");
        else                      asm volatile("s_waitcnt vmcnt(0)"  ::: "memory");
        __builtin_amdgcn_sched_barrier(0);

        const ushort* bp = (const ushort*)&buf[tc % 3][0];

        float cc[16];
        #pragma unroll
        for (int i = 0; i < 16; ++i) cc[i] = c_sh[hr * 16 + i];
        float xm[4];
        #pragma unroll
        for (int j = 0; j < 4; ++j) xm[j] = xm_s[tc * 16 + hr * 4 + j];

        float a0 = 0.f, a1 = 0.f, a2 = 0.f, a3 = 0.f;
        #pragma unroll
        for (int j = 0; j < 4; ++j) {   // J: m = hr*4+j, k = 4q..4q+3
            const uint2 u = *(const uint2*)(bp + (hr * 4 + j) * 64 + q * 4);
            a0 += xm[j] * blo(u.x); a1 += xm[j] * bhi(u.x);
            a2 += xm[j] * blo(u.y); a3 += xm[j] * bhi(u.y);
        }
        #pragma unroll
        for (int i = 0; i < 16; ++i) {  // R: h = hr*16+i
            const uint2 u = *(const uint2*)(bp + 1024 + (hr * 16 + i) * 64 + q * 4);
            a0 += cc[i] * blo(u.x); a1 += cc[i] * bhi(u.x);
            a2 += cc[i] * blo(u.y); a3 += cc[i] * bhi(u.y);
        }
        const uint2 uo = *(const uint2*)(bp + 5120 + q * 4);
        const float o0 = blo(uo.x), o1 = bhi(uo.x), o2 = blo(uo.y), o3 = bhi(uo.y);

        a0 += __shfl_xor(a0, 16); a1 += __shfl_xor(a1, 16);
        a2 += __shfl_xor(a2, 16); a3 += __shfl_xor(a3, 16);
        a0 += __shfl_xor(a0, 32); a1 += __shfl_xor(a1, 32);
        a2 += __shfl_xor(a2, 32); a3 += __shfl_xor(a3, 32);

        const float cn0 = (1.f - o0) * a0;
        const float cn1 = (1.f - o1) * a1;
        const float cn2 = (1.f - o2) * a2;
        const float cn3 = (1.f - o3) * a3;

        if (hr == 0) {
            *(float4*)&c_sh[q * 4] = make_float4(cn0, cn1, cn2, cn3);
            *(float4*)(cbase + ((size_t)b * T + t0 + tc) * H + q * 4) =
                make_float4(cn0, cn1, cn2, cn3);
        }
        if (t0 + tc == T - 1) {
            float v = o0 * a0 * wfc4.x + o1 * a1 * wfc4.y +
                      o2 * a2 * wfc4.z + o3 * a3 * wfc4.w;
            v += __shfl_xor(v, 1); v += __shfl_xor(v, 2);
            v += __shfl_xor(v, 4); v += __shfl_xor(v, 8);
            if (l == 0) out[b] = v + bfc0;
        }

        if (tc + 3 < chunk) {
            asm volatile("s_waitcnt lgkmcnt(0)" ::: "memory");
            DMA(tc + 3);
        }
    }
#undef DMA
}

// ---------------------------------------------------------------------------
extern "C" void kernel_launch(void* const* d_in, const int* in_sizes, int n_in,
                              void* d_out, int out_size, void* d_ws, size_t ws_size,
                              hipStream_t stream) {
    const float* x_m = (const float*)d_in[0];
    const float* x_a = (const float*)d_in[1];
    const float* Wj  = (const float*)d_in[2];
    const float* bj  = (const float*)d_in[3];
    const float* Wr  = (const float*)d_in[4];
    const float* br  = (const float*)d_in[5];
    const float* Wo  = (const float*)d_in[6];
    const float* bo  = (const float*)d_in[7];
    const float* Wfc = (const float*)d_in[8];
    const float* bfc = (const float*)d_in[9];
    float* out = (float*)d_out;
    unsigned char* ws = (unsigned char*)d_ws;

    // largest time-chunk (multiple of 32) whose G fits in the workspace
    int chunk = 256;
    while (chunk > 32 && OG + (size_t)(B * chunk / 16) * ROWBYTES > ws_size) chunk >>= 1;

    {   // bf16 conversion + bias concat
        const int total = 5184 * 32 + B * T * A + 5184;
        prep_kernel<<<(total + 255) / 256, 256, 0, stream>>>(
            x_a, Wj, Wr, Wo, bj, br, bo, ws);
    }

    for (int t0 = 0; t0 < T; t0 += chunk) {
        gate_kernel<<<(B * chunk) / 32, 256, 0, stream>>>(ws, t0, chunk);
        scan_kernel<<<64, 64, 0, stream>>>(
            ws, x_m, Wfc, bfc, out, t0, chunk, t0 == 0 ? 1 : 0);
    }
}